// Round 1
// baseline (936.600 us; speedup 1.0000x reference)
//
#include <hip/hip_runtime.h>

#define FEAT 64

// ---------------------------------------------------------------------------
// K1: xp = x @ W ; alpha_src[n] = xp[n,:]·a_src ; alpha_dst[n] = xp[n,:]·a_dst
// One wave per node. W staged in LDS (64x64 fp32 = 16 KB).
// ---------------------------------------------------------------------------
__global__ __launch_bounds__(256) void gemm_alpha_kernel(
    const float* __restrict__ x, const float* __restrict__ W,
    const float* __restrict__ a_src, const float* __restrict__ a_dst,
    float* __restrict__ xp, float* __restrict__ as_, float* __restrict__ ad_,
    int n)
{
    __shared__ float Wl[FEAT * FEAT];
    for (int i = threadIdx.x; i < FEAT * FEAT; i += 256) Wl[i] = W[i];
    __syncthreads();

    const int lane = threadIdx.x & 63;
    const int wave = threadIdx.x >> 6;
    const int node = blockIdx.x * 4 + wave;
    if (node >= n) return;

    const float xv = x[(size_t)node * FEAT + lane];
    float acc = 0.f;
#pragma unroll
    for (int k = 0; k < FEAT; ++k) {
        acc += __shfl(xv, k) * Wl[k * FEAT + lane];
    }
    xp[(size_t)node * FEAT + lane] = acc;

    float s1 = acc * a_src[lane];
    float s2 = acc * a_dst[lane];
#pragma unroll
    for (int off = 32; off > 0; off >>= 1) {
        s1 += __shfl_down(s1, off);
        s2 += __shfl_down(s2, off);
    }
    if (lane == 0) { as_[node] = s1; ad_[node] = s2; }
}

// ---------------------------------------------------------------------------
// K2: per edge e: w = exp(leaky_relu(as[src]+ad[dst]))
//     denom[dst] += w ; acc[dst,:] += w * xp[src,:]
// One wave per edge; lane f handles feature f. Self-loops are NOT processed
// here (folded into finalize).
// ---------------------------------------------------------------------------
__global__ __launch_bounds__(256) void edge_scatter_kernel(
    const int* __restrict__ src, const int* __restrict__ dst,
    const float* __restrict__ as_, const float* __restrict__ ad_,
    const float* __restrict__ xp, float* __restrict__ acc,
    float* __restrict__ denom, int E)
{
    const int lane = threadIdx.x & 63;
    const int wave = threadIdx.x >> 6;
    const int e = blockIdx.x * 4 + wave;
    if (e >= E) return;

    const int s = src[e];
    const int d = dst[e];
    float t = as_[s] + ad_[d];
    t = (t >= 0.f) ? t : 0.2f * t;
    const float w = __expf(t);

    if (lane == 0) atomicAdd(&denom[d], w);
    atomicAdd(&acc[(size_t)d * FEAT + lane], w * xp[(size_t)s * FEAT + lane]);
}

// ---------------------------------------------------------------------------
// K3: fold in self-loop, normalize, add bias, ReLU.
// h[n,f] = relu( (acc[n,f] + w_self*xp[n,f]) / (denom[n] + w_self) + b[f] )
// ---------------------------------------------------------------------------
__global__ __launch_bounds__(256) void finalize_kernel(
    const float* __restrict__ xp, const float* __restrict__ acc,
    const float* __restrict__ denom, const float* __restrict__ as_,
    const float* __restrict__ ad_, const float* __restrict__ b,
    float* __restrict__ h, int n)
{
    const int lane = threadIdx.x & 63;
    const int wave = threadIdx.x >> 6;
    const int node = blockIdx.x * 4 + wave;
    if (node >= n) return;

    float t = as_[node] + ad_[node];
    t = (t >= 0.f) ? t : 0.2f * t;
    const float w = __expf(t);

    const float num = acc[(size_t)node * FEAT + lane] + w * xp[(size_t)node * FEAT + lane];
    const float den = denom[node] + w;
    float v = num / den + b[lane];
    h[(size_t)node * FEAT + lane] = (v > 0.f) ? v : 0.f;
}

// ---------------------------------------------------------------------------
// K4: scatter-mean phase 1: gsum[batch[n],:] += h[n,:], gcnt[batch[n]] += 1
// ---------------------------------------------------------------------------
__global__ __launch_bounds__(256) void pool_scatter_kernel(
    const float* __restrict__ h, const int* __restrict__ batch,
    float* __restrict__ gsum, float* __restrict__ gcnt, int n)
{
    const int lane = threadIdx.x & 63;
    const int wave = threadIdx.x >> 6;
    const int node = blockIdx.x * 4 + wave;
    if (node >= n) return;

    const int g = batch[node];
    atomicAdd(&gsum[(size_t)g * FEAT + lane], h[(size_t)node * FEAT + lane]);
    if (lane == 0) atomicAdd(&gcnt[g], 1.f);
}

// ---------------------------------------------------------------------------
// K5: out = gsum / max(gcnt, 1)  (full overwrite of d_out)
// ---------------------------------------------------------------------------
__global__ __launch_bounds__(64) void pool_div_kernel(
    const float* __restrict__ gsum, const float* __restrict__ gcnt,
    float* __restrict__ out, int G)
{
    const int g = blockIdx.x;
    const int f = threadIdx.x;
    float c = gcnt[g];
    c = (c > 1.f) ? c : 1.f;
    out[(size_t)g * FEAT + f] = gsum[(size_t)g * FEAT + f] / c;
}

extern "C" void kernel_launch(void* const* d_in, const int* in_sizes, int n_in,
                              void* d_out, int out_size, void* d_ws, size_t ws_size,
                              hipStream_t stream)
{
    const float* x      = (const float*)d_in[0];
    const int*   ei     = (const int*)d_in[1];
    const int*   batch  = (const int*)d_in[2];
    const float* W1     = (const float*)d_in[3];
    const float* asrc1  = (const float*)d_in[4];
    const float* adst1  = (const float*)d_in[5];
    const float* b1     = (const float*)d_in[6];
    const float* W2     = (const float*)d_in[7];
    const float* asrc2  = (const float*)d_in[8];
    const float* adst2  = (const float*)d_in[9];
    const float* b2     = (const float*)d_in[10];

    const int N = in_sizes[2];          // 50000 nodes (batch array length)
    const int E = in_sizes[1] / 2;      // 800000 edges
    const int G = out_size / FEAT;      // 128 graphs

    const int* src = ei;
    const int* dst = ei + E;

    // Workspace layout (floats). acc|denom contiguous -> single memset/layer.
    float* ws    = (float*)d_ws;
    float* acc   = ws;                              // N*64
    float* denom = acc + (size_t)N * FEAT;          // N
    float* gsum  = denom + N;                       // G*64
    float* gcnt  = gsum + (size_t)G * FEAT;         // G
    float* xp    = gcnt + G;                        // N*64
    float* h     = xp + (size_t)N * FEAT;           // N*64
    float* as_   = h + (size_t)N * FEAT;            // N
    float* ad_   = as_ + N;                         // N

    const size_t accden_bytes = ((size_t)N * FEAT + N) * sizeof(float);
    const size_t pool_bytes   = ((size_t)G * FEAT + G) * sizeof(float);

    const int nodeBlocks = (N + 3) / 4;
    const int edgeBlocks = (E + 3) / 4;

    // ---- layer 1 ----
    hipMemsetAsync(acc, 0, accden_bytes, stream);
    hipMemsetAsync(gsum, 0, pool_bytes, stream);
    gemm_alpha_kernel<<<nodeBlocks, 256, 0, stream>>>(x, W1, asrc1, adst1, xp, as_, ad_, N);
    edge_scatter_kernel<<<edgeBlocks, 256, 0, stream>>>(src, dst, as_, ad_, xp, acc, denom, E);
    finalize_kernel<<<nodeBlocks, 256, 0, stream>>>(xp, acc, denom, as_, ad_, b1, h, N);

    // ---- layer 2 ----
    hipMemsetAsync(acc, 0, accden_bytes, stream);
    gemm_alpha_kernel<<<nodeBlocks, 256, 0, stream>>>(h, W2, asrc2, adst2, xp, as_, ad_, N);
    edge_scatter_kernel<<<edgeBlocks, 256, 0, stream>>>(src, dst, as_, ad_, xp, acc, denom, E);
    finalize_kernel<<<nodeBlocks, 256, 0, stream>>>(xp, acc, denom, as_, ad_, b2, h, N);

    // ---- graph mean pool ----
    pool_scatter_kernel<<<nodeBlocks, 256, 0, stream>>>(h, batch, gsum, gcnt, N);
    pool_div_kernel<<<G, FEAT, 0, stream>>>(gsum, gcnt, (float*)d_out, G);
}

// Round 2
// 435.323 us; speedup vs baseline: 2.1515x; 2.1515x over previous
//
#include <hip/hip_runtime.h>

#define FEAT 64

// ---------------------------------------------------------------------------
// K1: xp = x @ W ; alpha_src[n] = xp[n,:]·a_src ; alpha_dst[n] = xp[n,:]·a_dst
// One wave per node. W staged in LDS (64x64 fp32 = 16 KB).
// ---------------------------------------------------------------------------
__global__ __launch_bounds__(256) void gemm_alpha_kernel(
    const float* __restrict__ x, const float* __restrict__ W,
    const float* __restrict__ a_src, const float* __restrict__ a_dst,
    float* __restrict__ xp, float* __restrict__ as_, float* __restrict__ ad_,
    int n)
{
    __shared__ float Wl[FEAT * FEAT];
    for (int i = threadIdx.x; i < FEAT * FEAT; i += 256) Wl[i] = W[i];
    __syncthreads();

    const int lane = threadIdx.x & 63;
    const int wave = threadIdx.x >> 6;
    const int node = blockIdx.x * 4 + wave;
    if (node >= n) return;

    const float xv = x[(size_t)node * FEAT + lane];
    float acc = 0.f;
#pragma unroll
    for (int k = 0; k < FEAT; ++k) {
        acc += __shfl(xv, k) * Wl[k * FEAT + lane];
    }
    xp[(size_t)node * FEAT + lane] = acc;

    float s1 = acc * a_src[lane];
    float s2 = acc * a_dst[lane];
#pragma unroll
    for (int off = 32; off > 0; off >>= 1) {
        s1 += __shfl_down(s1, off);
        s2 += __shfl_down(s2, off);
    }
    if (lane == 0) { as_[node] = s1; ad_[node] = s2; }
}

// ---------------------------------------------------------------------------
// CSR build: histogram of dst
// ---------------------------------------------------------------------------
__global__ __launch_bounds__(256) void hist_kernel(
    const int* __restrict__ dst, int* __restrict__ deg, int E)
{
    int e = blockIdx.x * 256 + threadIdx.x;
    if (e < E) atomicAdd(&deg[dst[e]], 1);
}

// ---------------------------------------------------------------------------
// Hierarchical exclusive scan, step 1: per-256-block scan of deg -> off,
// block sums -> bsum.
// ---------------------------------------------------------------------------
__global__ __launch_bounds__(256) void scan_block_kernel(
    const int* __restrict__ deg, int* __restrict__ off,
    int* __restrict__ bsum, int n)
{
    __shared__ int s[256];
    const int t = threadIdx.x;
    const int i = blockIdx.x * 256 + t;
    int v = (i < n) ? deg[i] : 0;
    s[t] = v;
    __syncthreads();
    // Hillis-Steele inclusive scan
#pragma unroll
    for (int d = 1; d < 256; d <<= 1) {
        int add = (t >= d) ? s[t - d] : 0;
        __syncthreads();
        s[t] += add;
        __syncthreads();
    }
    if (i < n) off[i] = s[t] - v;           // exclusive
    if (t == 255) bsum[blockIdx.x] = s[255];
}

// step 2: exclusive scan of block sums (nb <= 256), single block
__global__ __launch_bounds__(256) void scan_partials_kernel(
    int* __restrict__ bsum, int nb)
{
    __shared__ int s[256];
    const int t = threadIdx.x;
    int v = (t < nb) ? bsum[t] : 0;
    s[t] = v;
    __syncthreads();
#pragma unroll
    for (int d = 1; d < 256; d <<= 1) {
        int add = (t >= d) ? s[t - d] : 0;
        __syncthreads();
        s[t] += add;
        __syncthreads();
    }
    if (t < nb) bsum[t] = s[t] - v;         // exclusive
}

// step 3: add block offsets; also init cursor copy and off[n] = E
__global__ __launch_bounds__(256) void scan_add_kernel(
    int* __restrict__ off, const int* __restrict__ bsum,
    int* __restrict__ cursor, int n, int E)
{
    int i = blockIdx.x * 256 + threadIdx.x;
    if (i < n) {
        int v = off[i] + bsum[i >> 8];
        off[i] = v;
        cursor[i] = v;
    }
    if (i == 0) off[n] = E;
}

// placement: esrc[pos] = src[e], grouped by dst
__global__ __launch_bounds__(256) void place_kernel(
    const int* __restrict__ src, const int* __restrict__ dst,
    int* __restrict__ cursor, int* __restrict__ esrc, int E)
{
    int e = blockIdx.x * 256 + threadIdx.x;
    if (e >= E) return;
    int pos = atomicAdd(&cursor[dst[e]], 1);
    esrc[pos] = src[e];
}

// ---------------------------------------------------------------------------
// Fused aggregate + finalize: one wave per dst node. Gather-based, no atomics.
// h[d,f] = relu( (sum_e w_e*xp[src_e,f] + w_self*xp[d,f]) / (sum w + w_self) + b[f] )
// ---------------------------------------------------------------------------
__global__ __launch_bounds__(256) void gat_aggregate_kernel(
    const int* __restrict__ off, const int* __restrict__ esrc,
    const float* __restrict__ as_, const float* __restrict__ ad_,
    const float* __restrict__ xp, const float* __restrict__ b,
    float* __restrict__ h, int n)
{
    const int lane = threadIdx.x & 63;
    const int wave = threadIdx.x >> 6;
    const int node = blockIdx.x * 4 + wave;
    if (node >= n) return;

    const int lo = off[node];
    const int hi = off[node + 1];
    const float adv = ad_[node];

    float acc = 0.f;
    float wsum = 0.f;

    for (int base = lo; base < hi; base += 64) {
        const int j = base + lane;
        int   s = 0;
        float w = 0.f;
        if (j < hi) {
            s = esrc[j];
            float t = as_[s] + adv;
            t = (t >= 0.f) ? t : 0.2f * t;
            w = __expf(t);
        }
        wsum += w;
        const int cnt = min(64, hi - base);
        for (int k = 0; k < cnt; ++k) {
            const int   sk = __shfl(s, k);
            const float wk = __shfl(w, k);
            acc += wk * xp[(size_t)sk * FEAT + lane];
        }
    }

    // total edge weight across lanes (butterfly -> all lanes)
#pragma unroll
    for (int o = 32; o > 0; o >>= 1) wsum += __shfl_xor(wsum, o);

    // self-loop
    float t = as_[node] + adv;
    t = (t >= 0.f) ? t : 0.2f * t;
    const float wself = __expf(t);

    const float num = acc + wself * xp[(size_t)node * FEAT + lane];
    const float den = wsum + wself;
    float v = num / den + b[lane];
    h[(size_t)node * FEAT + lane] = (v > 0.f) ? v : 0.f;
}

// ---------------------------------------------------------------------------
// Pool: batch is sorted -> one block per graph, binary-search bounds,
// direct sum + divide. No atomics; full overwrite of d_out.
// ---------------------------------------------------------------------------
__device__ __forceinline__ int lower_bound_i(const int* a, int n, int key)
{
    int lo = 0, hi = n;
    while (lo < hi) {
        int mid = (lo + hi) >> 1;
        if (a[mid] < key) lo = mid + 1; else hi = mid;
    }
    return lo;
}

__global__ __launch_bounds__(256) void pool_kernel(
    const float* __restrict__ h, const int* __restrict__ batch,
    float* __restrict__ out, int n)
{
    const int g = blockIdx.x;
    const int lane = threadIdx.x & 63;
    const int wave = threadIdx.x >> 6;

    const int lo = lower_bound_i(batch, n, g);
    const int hi = lower_bound_i(batch, n, g + 1);

    float sum = 0.f;
    for (int i = lo + wave; i < hi; i += 4)
        sum += h[(size_t)i * FEAT + lane];

    __shared__ float part[4][FEAT];
    part[wave][lane] = sum;
    __syncthreads();
    if (wave == 0) {
        float s = part[0][lane] + part[1][lane] + part[2][lane] + part[3][lane];
        float c = (float)(hi - lo);
        out[(size_t)g * FEAT + lane] = s / fmaxf(c, 1.f);
    }
}

extern "C" void kernel_launch(void* const* d_in, const int* in_sizes, int n_in,
                              void* d_out, int out_size, void* d_ws, size_t ws_size,
                              hipStream_t stream)
{
    const float* x      = (const float*)d_in[0];
    const int*   ei     = (const int*)d_in[1];
    const int*   batch  = (const int*)d_in[2];
    const float* W1     = (const float*)d_in[3];
    const float* asrc1  = (const float*)d_in[4];
    const float* adst1  = (const float*)d_in[5];
    const float* b1     = (const float*)d_in[6];
    const float* W2     = (const float*)d_in[7];
    const float* asrc2  = (const float*)d_in[8];
    const float* adst2  = (const float*)d_in[9];
    const float* b2     = (const float*)d_in[10];

    const int N = in_sizes[2];          // 50000 nodes
    const int E = in_sizes[1] / 2;      // 800000 edges
    const int G = out_size / FEAT;      // 128 graphs

    const int* src = ei;
    const int* dst = ei + E;

    // Workspace layout
    float* ws   = (float*)d_ws;
    float* xp   = ws;                              // N*64 f
    float* h    = xp + (size_t)N * FEAT;           // N*64 f
    float* as_  = h + (size_t)N * FEAT;            // N f
    float* ad_  = as_ + N;                         // N f
    int*   deg  = (int*)(ad_ + N);                 // N i  (becomes cursor)
    int*   off  = deg + N;                         // N+1 i
    int*   bsum = off + (N + 1);                   // 256 i
    int*   esrc = bsum + 256;                      // E i

    const int nodeBlocks = (N + 3) / 4;
    const int eBlocks    = (E + 255) / 256;
    const int nBlocks256 = (N + 255) / 256;        // also = scan blocks

    // ---- CSR build (once; reused by both layers) ----
    hipMemsetAsync(deg, 0, (size_t)N * sizeof(int), stream);
    hist_kernel<<<eBlocks, 256, 0, stream>>>(dst, deg, E);
    scan_block_kernel<<<nBlocks256, 256, 0, stream>>>(deg, off, bsum, N);
    scan_partials_kernel<<<1, 256, 0, stream>>>(bsum, nBlocks256);
    scan_add_kernel<<<nBlocks256, 256, 0, stream>>>(off, bsum, deg, N, E);
    place_kernel<<<eBlocks, 256, 0, stream>>>(src, dst, deg, esrc, E);

    // ---- layer 1 ----
    gemm_alpha_kernel<<<nodeBlocks, 256, 0, stream>>>(x, W1, asrc1, adst1, xp, as_, ad_, N);
    gat_aggregate_kernel<<<nodeBlocks, 256, 0, stream>>>(off, esrc, as_, ad_, xp, b1, h, N);

    // ---- layer 2 ----
    gemm_alpha_kernel<<<nodeBlocks, 256, 0, stream>>>(h, W2, asrc2, adst2, xp, as_, ad_, N);
    gat_aggregate_kernel<<<nodeBlocks, 256, 0, stream>>>(off, esrc, as_, ad_, xp, b2, h, N);

    // ---- graph mean pool ----
    pool_kernel<<<G, 256, 0, stream>>>(h, batch, (float*)d_out, N);
}

// Round 3
// 424.450 us; speedup vs baseline: 2.2066x; 1.0256x over previous
//
#include <hip/hip_runtime.h>

#define FEAT 64

// ---------------------------------------------------------------------------
// K1: xp = x @ W ; alpha_src[n] = xp[n,:]·a_src ; alpha_dst[n] = xp[n,:]·a_dst
// Tiled register-blocked GEMM: block = 256 threads = 64-node x 64-col tile.
// X staged transposed in LDS (stride 68: 16B-aligned float4, conflict-free),
// W staged row-major (b128 reads 2-way bank-aliased = free on gfx950).
// Each thread: 4 nodes x 4 cols micro-tile -> 16 independent FMA chains.
// ---------------------------------------------------------------------------
__global__ __launch_bounds__(256) void gemm_alpha_kernel(
    const float* __restrict__ x, const float* __restrict__ W,
    const float* __restrict__ a_src, const float* __restrict__ a_dst,
    float* __restrict__ xp, float* __restrict__ as_, float* __restrict__ ad_,
    int n)
{
    __shared__ float XT[FEAT][68];      // XT[k][row]
    __shared__ float Ws[FEAT][FEAT];    // Ws[k][col]

    const int t = threadIdx.x;
    const int row0 = blockIdx.x * 64;

    // stage W (4096 floats, 16 per thread as float4)
    for (int i = t; i < FEAT * 16; i += 256) {
        const int r = i >> 4, c = (i & 15) << 2;
        *(float4*)(&Ws[r][c]) = *(const float4*)(W + r * FEAT + c);
    }
    // stage X transposed
    for (int i = t; i < 64 * 16; i += 256) {
        const int r = i >> 4, c = (i & 15) << 2;
        const int gr = row0 + r;
        float4 v = make_float4(0.f, 0.f, 0.f, 0.f);
        if (gr < n) v = *(const float4*)(x + (size_t)gr * FEAT + c);
        XT[c + 0][r] = v.x; XT[c + 1][r] = v.y;
        XT[c + 2][r] = v.z; XT[c + 3][r] = v.w;
    }
    __syncthreads();

    const int ni = t >> 4;   // node group 0..15 (nodes 4*ni..4*ni+3)
    const int ci = t & 15;   // col group 0..15 (cols 4*ci..4*ci+3)

    float acc[4][4] = {};
#pragma unroll
    for (int k = 0; k < FEAT; ++k) {
        const float4 a = *(const float4*)(&XT[k][ni << 2]);
        const float4 b = *(const float4*)(&Ws[k][ci << 2]);
        acc[0][0] += a.x * b.x; acc[0][1] += a.x * b.y; acc[0][2] += a.x * b.z; acc[0][3] += a.x * b.w;
        acc[1][0] += a.y * b.x; acc[1][1] += a.y * b.y; acc[1][2] += a.y * b.z; acc[1][3] += a.y * b.w;
        acc[2][0] += a.z * b.x; acc[2][1] += a.z * b.y; acc[2][2] += a.z * b.z; acc[2][3] += a.z * b.w;
        acc[3][0] += a.w * b.x; acc[3][1] += a.w * b.y; acc[3][2] += a.w * b.z; acc[3][3] += a.w * b.w;
    }

    // attention vector slices for this thread's 4 cols
    const float4 asv = *(const float4*)(a_src + (ci << 2));
    const float4 adv = *(const float4*)(a_dst + (ci << 2));

#pragma unroll
    for (int j = 0; j < 4; ++j) {
        const int node = row0 + (ni << 2) + j;
        if (node < n) {
            *(float4*)(xp + (size_t)node * FEAT + (ci << 2)) =
                make_float4(acc[j][0], acc[j][1], acc[j][2], acc[j][3]);
        }
        float s1 = acc[j][0] * asv.x + acc[j][1] * asv.y + acc[j][2] * asv.z + acc[j][3] * asv.w;
        float s2 = acc[j][0] * adv.x + acc[j][1] * adv.y + acc[j][2] * adv.z + acc[j][3] * adv.w;
        // reduce across the 16-lane ci segment (aligned, so plain shfl_down works)
#pragma unroll
        for (int o = 8; o > 0; o >>= 1) {
            s1 += __shfl_down(s1, o);
            s2 += __shfl_down(s2, o);
        }
        if (ci == 0 && node < n) { as_[node] = s1; ad_[node] = s2; }
    }
}

// ---------------------------------------------------------------------------
// CSR build: histogram of dst
// ---------------------------------------------------------------------------
__global__ __launch_bounds__(256) void hist_kernel(
    const int* __restrict__ dst, int* __restrict__ deg, int E)
{
    int e = blockIdx.x * 256 + threadIdx.x;
    if (e < E) atomicAdd(&deg[dst[e]], 1);
}

// Hierarchical exclusive scan, step 1
__global__ __launch_bounds__(256) void scan_block_kernel(
    const int* __restrict__ deg, int* __restrict__ off,
    int* __restrict__ bsum, int n)
{
    __shared__ int s[256];
    const int t = threadIdx.x;
    const int i = blockIdx.x * 256 + t;
    int v = (i < n) ? deg[i] : 0;
    s[t] = v;
    __syncthreads();
#pragma unroll
    for (int d = 1; d < 256; d <<= 1) {
        int add = (t >= d) ? s[t - d] : 0;
        __syncthreads();
        s[t] += add;
        __syncthreads();
    }
    if (i < n) off[i] = s[t] - v;
    if (t == 255) bsum[blockIdx.x] = s[255];
}

// step 2: scan of block sums (nb <= 256)
__global__ __launch_bounds__(256) void scan_partials_kernel(
    int* __restrict__ bsum, int nb)
{
    __shared__ int s[256];
    const int t = threadIdx.x;
    int v = (t < nb) ? bsum[t] : 0;
    s[t] = v;
    __syncthreads();
#pragma unroll
    for (int d = 1; d < 256; d <<= 1) {
        int add = (t >= d) ? s[t - d] : 0;
        __syncthreads();
        s[t] += add;
        __syncthreads();
    }
    if (t < nb) bsum[t] = s[t] - v;
}

// step 3: add block offsets; init cursor; off[n] = E
__global__ __launch_bounds__(256) void scan_add_kernel(
    int* __restrict__ off, const int* __restrict__ bsum,
    int* __restrict__ cursor, int n, int E)
{
    int i = blockIdx.x * 256 + threadIdx.x;
    if (i < n) {
        int v = off[i] + bsum[i >> 8];
        off[i] = v;
        cursor[i] = v;
    }
    if (i == 0) off[n] = E;
}

// placement: esrc[pos] = src[e], grouped by dst
__global__ __launch_bounds__(256) void place_kernel(
    const int* __restrict__ src, const int* __restrict__ dst,
    int* __restrict__ cursor, int* __restrict__ esrc, int E)
{
    int e = blockIdx.x * 256 + threadIdx.x;
    if (e >= E) return;
    int pos = atomicAdd(&cursor[dst[e]], 1);
    esrc[pos] = src[e];
}

// ---------------------------------------------------------------------------
// Fused aggregate + finalize: one wave per dst node, gather-based.
// (s,w) staged in wave-private LDS slice -> broadcast scalar reads (no
// bpermute); inner loop unrolled x4 with independent accumulators so 4 L2
// row-gathers are in flight.
// ---------------------------------------------------------------------------
__global__ __launch_bounds__(256) void gat_aggregate_kernel(
    const int* __restrict__ off, const int* __restrict__ esrc,
    const float* __restrict__ as_, const float* __restrict__ ad_,
    const float* __restrict__ xp, const float* __restrict__ b,
    float* __restrict__ h, int n)
{
    __shared__ int   sh_s[4][64];
    __shared__ float sh_w[4][64];

    const int lane = threadIdx.x & 63;
    const int wave = threadIdx.x >> 6;
    const int node = blockIdx.x * 4 + wave;
    if (node >= n) return;

    const int lo = off[node];
    const int hi = off[node + 1];
    const float adv = ad_[node];

    float acc0 = 0.f, acc1 = 0.f, acc2 = 0.f, acc3 = 0.f;
    float wsum = 0.f;

    for (int base = lo; base < hi; base += 64) {
        const int j = base + lane;
        int   s = 0;
        float w = 0.f;
        if (j < hi) {
            s = esrc[j];
            float t = as_[s] + adv;
            t = (t >= 0.f) ? t : 0.2f * t;
            w = __expf(t);
        }
        wsum += w;
        sh_s[wave][lane] = s;
        sh_w[wave][lane] = w;   // wave-private slice: no __syncthreads needed

        const int cnt = min(64, hi - base);
        int k = 0;
        for (; k + 4 <= cnt; k += 4) {
            const int   s0 = sh_s[wave][k + 0], s1 = sh_s[wave][k + 1];
            const int   s2 = sh_s[wave][k + 2], s3 = sh_s[wave][k + 3];
            const float w0 = sh_w[wave][k + 0], w1 = sh_w[wave][k + 1];
            const float w2 = sh_w[wave][k + 2], w3 = sh_w[wave][k + 3];
            acc0 += w0 * xp[(size_t)s0 * FEAT + lane];
            acc1 += w1 * xp[(size_t)s1 * FEAT + lane];
            acc2 += w2 * xp[(size_t)s2 * FEAT + lane];
            acc3 += w3 * xp[(size_t)s3 * FEAT + lane];
        }
        for (; k < cnt; ++k) {
            acc0 += sh_w[wave][k] * xp[(size_t)sh_s[wave][k] * FEAT + lane];
        }
    }

    float acc = (acc0 + acc1) + (acc2 + acc3);

#pragma unroll
    for (int o = 32; o > 0; o >>= 1) wsum += __shfl_xor(wsum, o);

    // self-loop
    float t = as_[node] + adv;
    t = (t >= 0.f) ? t : 0.2f * t;
    const float wself = __expf(t);

    const float num = acc + wself * xp[(size_t)node * FEAT + lane];
    const float den = wsum + wself;
    float v = num / den + b[lane];
    h[(size_t)node * FEAT + lane] = (v > 0.f) ? v : 0.f;
}

// ---------------------------------------------------------------------------
// Pool: batch sorted -> one block per graph, binary-search bounds, direct sum.
// ---------------------------------------------------------------------------
__device__ __forceinline__ int lower_bound_i(const int* a, int n, int key)
{
    int lo = 0, hi = n;
    while (lo < hi) {
        int mid = (lo + hi) >> 1;
        if (a[mid] < key) lo = mid + 1; else hi = mid;
    }
    return lo;
}

__global__ __launch_bounds__(256) void pool_kernel(
    const float* __restrict__ h, const int* __restrict__ batch,
    float* __restrict__ out, int n)
{
    const int g = blockIdx.x;
    const int lane = threadIdx.x & 63;
    const int wave = threadIdx.x >> 6;

    const int lo = lower_bound_i(batch, n, g);
    const int hi = lower_bound_i(batch, n, g + 1);

    float sum = 0.f;
    for (int i = lo + wave; i < hi; i += 4)
        sum += h[(size_t)i * FEAT + lane];

    __shared__ float part[4][FEAT];
    part[wave][lane] = sum;
    __syncthreads();
    if (wave == 0) {
        float s = part[0][lane] + part[1][lane] + part[2][lane] + part[3][lane];
        float c = (float)(hi - lo);
        out[(size_t)g * FEAT + lane] = s / fmaxf(c, 1.f);
    }
}

extern "C" void kernel_launch(void* const* d_in, const int* in_sizes, int n_in,
                              void* d_out, int out_size, void* d_ws, size_t ws_size,
                              hipStream_t stream)
{
    const float* x      = (const float*)d_in[0];
    const int*   ei     = (const int*)d_in[1];
    const int*   batch  = (const int*)d_in[2];
    const float* W1     = (const float*)d_in[3];
    const float* asrc1  = (const float*)d_in[4];
    const float* adst1  = (const float*)d_in[5];
    const float* b1     = (const float*)d_in[6];
    const float* W2     = (const float*)d_in[7];
    const float* asrc2  = (const float*)d_in[8];
    const float* adst2  = (const float*)d_in[9];
    const float* b2     = (const float*)d_in[10];

    const int N = in_sizes[2];          // 50000 nodes
    const int E = in_sizes[1] / 2;      // 800000 edges
    const int G = out_size / FEAT;      // 128 graphs

    const int* src = ei;
    const int* dst = ei + E;

    // Workspace layout
    float* ws   = (float*)d_ws;
    float* xp   = ws;                              // N*64 f
    float* h    = xp + (size_t)N * FEAT;           // N*64 f
    float* as_  = h + (size_t)N * FEAT;            // N f
    float* ad_  = as_ + N;                         // N f
    int*   deg  = (int*)(ad_ + N);                 // N i (becomes cursor)
    int*   off  = deg + N;                         // N+1 i
    int*   bsum = off + (N + 1);                   // 256 i
    int*   esrc = bsum + 256;                      // E i

    const int gemmBlocks = (N + 63) / 64;
    const int nodeBlocks = (N + 3) / 4;
    const int eBlocks    = (E + 255) / 256;
    const int nBlocks256 = (N + 255) / 256;

    // ---- CSR build (once; reused by both layers) ----
    hipMemsetAsync(deg, 0, (size_t)N * sizeof(int), stream);
    hist_kernel<<<eBlocks, 256, 0, stream>>>(dst, deg, E);
    scan_block_kernel<<<nBlocks256, 256, 0, stream>>>(deg, off, bsum, N);
    scan_partials_kernel<<<1, 256, 0, stream>>>(bsum, nBlocks256);
    scan_add_kernel<<<nBlocks256, 256, 0, stream>>>(off, bsum, deg, N, E);
    place_kernel<<<eBlocks, 256, 0, stream>>>(src, dst, deg, esrc, E);

    // ---- layer 1 ----
    gemm_alpha_kernel<<<gemmBlocks, 256, 0, stream>>>(x, W1, asrc1, adst1, xp, as_, ad_, N);
    gat_aggregate_kernel<<<nodeBlocks, 256, 0, stream>>>(off, esrc, as_, ad_, xp, b1, h, N);

    // ---- layer 2 ----
    gemm_alpha_kernel<<<gemmBlocks, 256, 0, stream>>>(h, W2, asrc2, adst2, xp, as_, ad_, N);
    gat_aggregate_kernel<<<nodeBlocks, 256, 0, stream>>>(off, esrc, as_, ad_, xp, b2, h, N);

    // ---- graph mean pool ----
    pool_kernel<<<G, 256, 0, stream>>>(h, batch, (float*)d_out, N);
}

// Round 4
// 307.229 us; speedup vs baseline: 3.0485x; 1.3815x over previous
//
#include <hip/hip_runtime.h>

#define FEAT 64

// ---------------------------------------------------------------------------
// K1: xp = x @ W ; alpha_src[n] = xp[n,:]·a_src ; alpha_dst[n] = xp[n,:]·a_dst
// Tiled register-blocked GEMM: block = 256 threads = 64-node x 64-col tile.
// X staged transposed in LDS (stride 68, 16B-aligned), W row-major.
// Each thread: 4 nodes x 4 cols micro-tile.
// unroll capped at 4 + launch_bounds(256,4): full unroll at 64 made the
// compiler hoist all LDS loads -> 256 VGPRs -> ~100MB scratch spill traffic
// (R3 counters: WRITE_SIZE 100MB vs 13MB expected, occupancy 8.5%).
// ---------------------------------------------------------------------------
__global__ __launch_bounds__(256, 4) void gemm_alpha_kernel(
    const float* __restrict__ x, const float* __restrict__ W,
    const float* __restrict__ a_src, const float* __restrict__ a_dst,
    float* __restrict__ xp, float* __restrict__ as_, float* __restrict__ ad_,
    int n)
{
    __shared__ float XT[FEAT][68];      // XT[k][row]
    __shared__ float Ws[FEAT][FEAT];    // Ws[k][col]

    const int t = threadIdx.x;
    const int row0 = blockIdx.x * 64;

    // stage W (4096 floats, 16 per thread as float4)
    for (int i = t; i < FEAT * 16; i += 256) {
        const int r = i >> 4, c = (i & 15) << 2;
        *(float4*)(&Ws[r][c]) = *(const float4*)(W + r * FEAT + c);
    }
    // stage X transposed (coalesced global read; LDS write conflicts are
    // once-per-block staging cost, ~3% — accepted)
    for (int i = t; i < 64 * 16; i += 256) {
        const int r = i >> 4, c = (i & 15) << 2;
        const int gr = row0 + r;
        float4 v = make_float4(0.f, 0.f, 0.f, 0.f);
        if (gr < n) v = *(const float4*)(x + (size_t)gr * FEAT + c);
        XT[c + 0][r] = v.x; XT[c + 1][r] = v.y;
        XT[c + 2][r] = v.z; XT[c + 3][r] = v.w;
    }
    __syncthreads();

    const int ni = t >> 4;   // node group 0..15 (nodes 4*ni..4*ni+3)
    const int ci = t & 15;   // col group 0..15 (cols 4*ci..4*ci+3)

    float acc[4][4] = {};
#pragma unroll 4
    for (int k = 0; k < FEAT; ++k) {
        const float4 a = *(const float4*)(&XT[k][ni << 2]);
        const float4 b = *(const float4*)(&Ws[k][ci << 2]);
        acc[0][0] += a.x * b.x; acc[0][1] += a.x * b.y; acc[0][2] += a.x * b.z; acc[0][3] += a.x * b.w;
        acc[1][0] += a.y * b.x; acc[1][1] += a.y * b.y; acc[1][2] += a.y * b.z; acc[1][3] += a.y * b.w;
        acc[2][0] += a.z * b.x; acc[2][1] += a.z * b.y; acc[2][2] += a.z * b.z; acc[2][3] += a.z * b.w;
        acc[3][0] += a.w * b.x; acc[3][1] += a.w * b.y; acc[3][2] += a.w * b.z; acc[3][3] += a.w * b.w;
    }

    // attention vector slices for this thread's 4 cols
    const float4 asv = *(const float4*)(a_src + (ci << 2));
    const float4 adv = *(const float4*)(a_dst + (ci << 2));

#pragma unroll
    for (int j = 0; j < 4; ++j) {
        const int node = row0 + (ni << 2) + j;
        if (node < n) {
            *(float4*)(xp + (size_t)node * FEAT + (ci << 2)) =
                make_float4(acc[j][0], acc[j][1], acc[j][2], acc[j][3]);
        }
        float s1 = acc[j][0] * asv.x + acc[j][1] * asv.y + acc[j][2] * asv.z + acc[j][3] * asv.w;
        float s2 = acc[j][0] * adv.x + acc[j][1] * adv.y + acc[j][2] * adv.z + acc[j][3] * adv.w;
        // reduce across the 16-lane ci segment (segments are 16-aligned)
#pragma unroll
        for (int o = 8; o > 0; o >>= 1) {
            s1 += __shfl_down(s1, o);
            s2 += __shfl_down(s2, o);
        }
        if (ci == 0 && node < n) { as_[node] = s1; ad_[node] = s2; }
    }
}

// ---------------------------------------------------------------------------
// CSR build: histogram of dst
// ---------------------------------------------------------------------------
__global__ __launch_bounds__(256) void hist_kernel(
    const int* __restrict__ dst, int* __restrict__ deg, int E)
{
    int e = blockIdx.x * 256 + threadIdx.x;
    if (e < E) atomicAdd(&deg[dst[e]], 1);
}

// Hierarchical exclusive scan, step 1
__global__ __launch_bounds__(256) void scan_block_kernel(
    const int* __restrict__ deg, int* __restrict__ off,
    int* __restrict__ bsum, int n)
{
    __shared__ int s[256];
    const int t = threadIdx.x;
    const int i = blockIdx.x * 256 + t;
    int v = (i < n) ? deg[i] : 0;
    s[t] = v;
    __syncthreads();
#pragma unroll
    for (int d = 1; d < 256; d <<= 1) {
        int add = (t >= d) ? s[t - d] : 0;
        __syncthreads();
        s[t] += add;
        __syncthreads();
    }
    if (i < n) off[i] = s[t] - v;
    if (t == 255) bsum[blockIdx.x] = s[255];
}

// step 2: scan of block sums (nb <= 256)
__global__ __launch_bounds__(256) void scan_partials_kernel(
    int* __restrict__ bsum, int nb)
{
    __shared__ int s[256];
    const int t = threadIdx.x;
    int v = (t < nb) ? bsum[t] : 0;
    s[t] = v;
    __syncthreads();
#pragma unroll
    for (int d = 1; d < 256; d <<= 1) {
        int add = (t >= d) ? s[t - d] : 0;
        __syncthreads();
        s[t] += add;
        __syncthreads();
    }
    if (t < nb) bsum[t] = s[t] - v;
}

// step 3: add block offsets; init cursor; off[n] = E
__global__ __launch_bounds__(256) void scan_add_kernel(
    int* __restrict__ off, const int* __restrict__ bsum,
    int* __restrict__ cursor, int n, int E)
{
    int i = blockIdx.x * 256 + threadIdx.x;
    if (i < n) {
        int v = off[i] + bsum[i >> 8];
        off[i] = v;
        cursor[i] = v;
    }
    if (i == 0) off[n] = E;
}

// placement: esrc[pos] = src[e], grouped by dst
__global__ __launch_bounds__(256) void place_kernel(
    const int* __restrict__ src, const int* __restrict__ dst,
    int* __restrict__ cursor, int* __restrict__ esrc, int E)
{
    int e = blockIdx.x * 256 + threadIdx.x;
    if (e >= E) return;
    int pos = atomicAdd(&cursor[dst[e]], 1);
    esrc[pos] = src[e];
}

// ---------------------------------------------------------------------------
// Fused aggregate + finalize: one wave per dst node, gather-based.
// (s,w) staged in wave-private LDS slice; inner loop unrolled x4 with
// independent accumulators so 4 L2 row-gathers are in flight.
// ---------------------------------------------------------------------------
__global__ __launch_bounds__(256) void gat_aggregate_kernel(
    const int* __restrict__ off, const int* __restrict__ esrc,
    const float* __restrict__ as_, const float* __restrict__ ad_,
    const float* __restrict__ xp, const float* __restrict__ b,
    float* __restrict__ h, int n)
{
    __shared__ int   sh_s[4][64];
    __shared__ float sh_w[4][64];

    const int lane = threadIdx.x & 63;
    const int wave = threadIdx.x >> 6;
    const int node = blockIdx.x * 4 + wave;
    if (node >= n) return;

    const int lo = off[node];
    const int hi = off[node + 1];
    const float adv = ad_[node];

    float acc0 = 0.f, acc1 = 0.f, acc2 = 0.f, acc3 = 0.f;
    float wsum = 0.f;

    for (int base = lo; base < hi; base += 64) {
        const int j = base + lane;
        int   s = 0;
        float w = 0.f;
        if (j < hi) {
            s = esrc[j];
            float t = as_[s] + adv;
            t = (t >= 0.f) ? t : 0.2f * t;
            w = __expf(t);
        }
        wsum += w;
        sh_s[wave][lane] = s;
        sh_w[wave][lane] = w;   // wave-private slice: no __syncthreads needed

        const int cnt = min(64, hi - base);
        int k = 0;
        for (; k + 4 <= cnt; k += 4) {
            const int   s0 = sh_s[wave][k + 0], s1 = sh_s[wave][k + 1];
            const int   s2 = sh_s[wave][k + 2], s3 = sh_s[wave][k + 3];
            const float w0 = sh_w[wave][k + 0], w1 = sh_w[wave][k + 1];
            const float w2 = sh_w[wave][k + 2], w3 = sh_w[wave][k + 3];
            acc0 += w0 * xp[(size_t)s0 * FEAT + lane];
            acc1 += w1 * xp[(size_t)s1 * FEAT + lane];
            acc2 += w2 * xp[(size_t)s2 * FEAT + lane];
            acc3 += w3 * xp[(size_t)s3 * FEAT + lane];
        }
        for (; k < cnt; ++k) {
            acc0 += sh_w[wave][k] * xp[(size_t)sh_s[wave][k] * FEAT + lane];
        }
    }

    float acc = (acc0 + acc1) + (acc2 + acc3);

#pragma unroll
    for (int o = 32; o > 0; o >>= 1) wsum += __shfl_xor(wsum, o);

    // self-loop
    float t = as_[node] + adv;
    t = (t >= 0.f) ? t : 0.2f * t;
    const float wself = __expf(t);

    const float num = acc + wself * xp[(size_t)node * FEAT + lane];
    const float den = wsum + wself;
    float v = num / den + b[lane];
    h[(size_t)node * FEAT + lane] = (v > 0.f) ? v : 0.f;
}

// ---------------------------------------------------------------------------
// Pool: batch sorted -> one block per graph, binary-search bounds, direct sum.
// ---------------------------------------------------------------------------
__device__ __forceinline__ int lower_bound_i(const int* a, int n, int key)
{
    int lo = 0, hi = n;
    while (lo < hi) {
        int mid = (lo + hi) >> 1;
        if (a[mid] < key) lo = mid + 1; else hi = mid;
    }
    return lo;
}

__global__ __launch_bounds__(256) void pool_kernel(
    const float* __restrict__ h, const int* __restrict__ batch,
    float* __restrict__ out, int n)
{
    const int g = blockIdx.x;
    const int lane = threadIdx.x & 63;
    const int wave = threadIdx.x >> 6;

    const int lo = lower_bound_i(batch, n, g);
    const int hi = lower_bound_i(batch, n, g + 1);

    float sum = 0.f;
    for (int i = lo + wave; i < hi; i += 4)
        sum += h[(size_t)i * FEAT + lane];

    __shared__ float part[4][FEAT];
    part[wave][lane] = sum;
    __syncthreads();
    if (wave == 0) {
        float s = part[0][lane] + part[1][lane] + part[2][lane] + part[3][lane];
        float c = (float)(hi - lo);
        out[(size_t)g * FEAT + lane] = s / fmaxf(c, 1.f);
    }
}

extern "C" void kernel_launch(void* const* d_in, const int* in_sizes, int n_in,
                              void* d_out, int out_size, void* d_ws, size_t ws_size,
                              hipStream_t stream)
{
    const float* x      = (const float*)d_in[0];
    const int*   ei     = (const int*)d_in[1];
    const int*   batch  = (const int*)d_in[2];
    const float* W1     = (const float*)d_in[3];
    const float* asrc1  = (const float*)d_in[4];
    const float* adst1  = (const float*)d_in[5];
    const float* b1     = (const float*)d_in[6];
    const float* W2     = (const float*)d_in[7];
    const float* asrc2  = (const float*)d_in[8];
    const float* adst2  = (const float*)d_in[9];
    const float* b2     = (const float*)d_in[10];

    const int N = in_sizes[2];          // 50000 nodes
    const int E = in_sizes[1] / 2;      // 800000 edges
    const int G = out_size / FEAT;      // 128 graphs

    const int* src = ei;
    const int* dst = ei + E;

    // Workspace layout
    float* ws   = (float*)d_ws;
    float* xp   = ws;                              // N*64 f
    float* h    = xp + (size_t)N * FEAT;           // N*64 f
    float* as_  = h + (size_t)N * FEAT;            // N f
    float* ad_  = as_ + N;                         // N f
    int*   deg  = (int*)(ad_ + N);                 // N i (becomes cursor)
    int*   off  = deg + N;                         // N+1 i
    int*   bsum = off + (N + 1);                   // 256 i
    int*   esrc = bsum + 256;                      // E i

    const int gemmBlocks = (N + 63) / 64;
    const int nodeBlocks = (N + 3) / 4;
    const int eBlocks    = (E + 255) / 256;
    const int nBlocks256 = (N + 255) / 256;

    // ---- CSR build (once; reused by both layers) ----
    hipMemsetAsync(deg, 0, (size_t)N * sizeof(int), stream);
    hist_kernel<<<eBlocks, 256, 0, stream>>>(dst, deg, E);
    scan_block_kernel<<<nBlocks256, 256, 0, stream>>>(deg, off, bsum, N);
    scan_partials_kernel<<<1, 256, 0, stream>>>(bsum, nBlocks256);
    scan_add_kernel<<<nBlocks256, 256, 0, stream>>>(off, bsum, deg, N, E);
    place_kernel<<<eBlocks, 256, 0, stream>>>(src, dst, deg, esrc, E);

    // ---- layer 1 ----
    gemm_alpha_kernel<<<gemmBlocks, 256, 0, stream>>>(x, W1, asrc1, adst1, xp, as_, ad_, N);
    gat_aggregate_kernel<<<nodeBlocks, 256, 0, stream>>>(off, esrc, as_, ad_, xp, b1, h, N);

    // ---- layer 2 ----
    gemm_alpha_kernel<<<gemmBlocks, 256, 0, stream>>>(h, W2, asrc2, adst2, xp, as_, ad_, N);
    gat_aggregate_kernel<<<nodeBlocks, 256, 0, stream>>>(off, esrc, as_, ad_, xp, b2, h, N);

    // ---- graph mean pool ----
    pool_kernel<<<G, 256, 0, stream>>>(h, batch, (float*)d_out, N);
}